// Round 1
// baseline (3590.217 us; speedup 1.0000x reference)
//
#include <hip/hip_runtime.h>
#include <math.h>

#define N_NODES 100000
#define N_EDGES 400000
#define HDIM    128
#define GROUPS  4
#define KP1     6      // K+1 coefficients per group
#define RMS_EPS 1.1920929e-07f

// ---------------------------------------------------------------------------
// scatter: out[dst] += x[src] * ew   (32 threads per edge, float4 per lane)
// ---------------------------------------------------------------------------
__global__ void scatter_kernel(const float* __restrict__ x,
                               const int* __restrict__ src,
                               const int* __restrict__ dst,
                               const float* __restrict__ ew,
                               float* __restrict__ out) {
    int t = blockIdx.x * blockDim.x + threadIdx.x;
    int e = t >> 5;            // 32 threads per edge
    int lane = t & 31;
    if (e >= N_EDGES) return;
    int s = src[e];
    int d = dst[e];
    float w = ew[e];
    const float4 v = *reinterpret_cast<const float4*>(x + (size_t)s * HDIM + lane * 4);
    float* o = out + (size_t)d * HDIM + lane * 4;
    atomicAdd(o + 0, v.x * w);
    atomicAdd(o + 1, v.y * w);
    atomicAdd(o + 2, v.z * w);
    atomicAdd(o + 3, v.w * w);
}

// ---------------------------------------------------------------------------
// init: out = c[g][0]*x + c[g][1]*T1     (float4 per thread)
// ---------------------------------------------------------------------------
__global__ void init_kernel(const float* __restrict__ x,
                            const float* __restrict__ t1,
                            const float* __restrict__ cheb,
                            float* __restrict__ out) {
    size_t i = (size_t)blockIdx.x * blockDim.x + threadIdx.x;   // float4 index
    const size_t total = (size_t)N_NODES * HDIM / 4;
    if (i >= total) return;
    int g = ((int)(i & 31)) >> 3;   // float4-within-row 0..31 -> group 0..3
    float c0 = cheb[g * KP1 + 0];
    float c1 = cheb[g * KP1 + 1];
    float4 xv = reinterpret_cast<const float4*>(x)[i];
    float4 tv = reinterpret_cast<const float4*>(t1)[i];
    float4 o;
    o.x = c0 * xv.x + c1 * tv.x;
    o.y = c0 * xv.y + c1 * tv.y;
    o.z = c0 * xv.z + c1 * tv.z;
    o.w = c0 * xv.w + c1 * tv.w;
    reinterpret_cast<float4*>(out)[i] = o;
}

// ---------------------------------------------------------------------------
// step: T_curr = 2*S - T_prev2 (in place over S); out += c[g][k] * T_curr
// ---------------------------------------------------------------------------
__global__ void step_kernel(float* __restrict__ tc,          // holds S, becomes T_curr
                            const float* __restrict__ tp2,
                            const float* __restrict__ cheb,
                            int k,
                            float* __restrict__ out) {
    size_t i = (size_t)blockIdx.x * blockDim.x + threadIdx.x;
    const size_t total = (size_t)N_NODES * HDIM / 4;
    if (i >= total) return;
    int g = ((int)(i & 31)) >> 3;
    float ck = cheb[g * KP1 + k];
    float4 s  = reinterpret_cast<float4*>(tc)[i];
    float4 p  = reinterpret_cast<const float4*>(tp2)[i];
    float4 t;
    t.x = 2.0f * s.x - p.x;
    t.y = 2.0f * s.y - p.y;
    t.z = 2.0f * s.z - p.z;
    t.w = 2.0f * s.w - p.w;
    reinterpret_cast<float4*>(tc)[i] = t;
    float4 o = reinterpret_cast<float4*>(out)[i];
    o.x += ck * t.x;
    o.y += ck * t.y;
    o.z += ck * t.z;
    o.w += ck * t.w;
    reinterpret_cast<float4*>(out)[i] = o;
}

// ---------------------------------------------------------------------------
// final: group scale/bias -> RMSNorm(affine) -> SiLU   (one wave64 per row)
// ---------------------------------------------------------------------------
__global__ void norm_kernel(float* __restrict__ out,
                            const float* __restrict__ gscale,
                            const float* __restrict__ gbias,
                            const float* __restrict__ rmsw) {
    int row  = blockIdx.x * 4 + (threadIdx.x >> 6);   // 4 rows (waves) per block
    int lane = threadIdx.x & 63;
    if (row >= N_NODES) return;
    float* rp = out + (size_t)row * HDIM + lane * 2;
    float2 v = *reinterpret_cast<float2*>(rp);
    int g = (lane * 2) >> 5;   // group index (GC=32)
    float sc = gscale[g];
    float bi = gbias[g];
    v.x = v.x * sc + bi;
    v.y = v.y * sc + bi;
    float ss = v.x * v.x + v.y * v.y;
    #pragma unroll
    for (int m = 1; m < 64; m <<= 1)
        ss += __shfl_xor(ss, m, 64);
    float r = rsqrtf(ss * (1.0f / HDIM) + RMS_EPS);
    float wa = rmsw[lane * 2 + 0];
    float wb = rmsw[lane * 2 + 1];
    float a = v.x * r * wa;
    float b = v.y * r * wb;
    // SiLU
    a = a / (1.0f + expf(-a));
    b = b / (1.0f + expf(-b));
    float2 o = {a, b};
    *reinterpret_cast<float2*>(rp) = o;
}

// ---------------------------------------------------------------------------
extern "C" void kernel_launch(void* const* d_in, const int* in_sizes, int n_in,
                              void* d_out, int out_size, void* d_ws, size_t ws_size,
                              hipStream_t stream) {
    const float* x      = (const float*)d_in[0];
    const float* ew     = (const float*)d_in[1];
    const float* cheb   = (const float*)d_in[2];
    const float* gscale = (const float*)d_in[3];
    const float* gbias  = (const float*)d_in[4];
    const float* rmsw   = (const float*)d_in[5];
    const int*   eidx   = (const int*)d_in[6];
    const int*   src    = eidx;               // edge_index[0]
    const int*   dst    = eidx + N_EDGES;     // edge_index[1]
    float* out = (float*)d_out;

    float* W0 = (float*)d_ws;
    float* W1 = W0 + (size_t)N_NODES * HDIM;
    float* W2 = W1 + (size_t)N_NODES * HDIM;
    const size_t row_bytes = (size_t)N_NODES * HDIM * sizeof(float);

    const int TB = 256;
    const int scatter_blocks = (N_EDGES * 32 + TB - 1) / TB;       // 50000
    const int elem_blocks    = ((N_NODES * HDIM / 4) + TB - 1) / TB; // 12500
    const int norm_blocks    = (N_NODES + 3) / 4;                   // 25000

    // T1 = prop(x) -> W0 ; out = c0*x + c1*T1
    hipMemsetAsync(W0, 0, row_bytes, stream);
    scatter_kernel<<<scatter_blocks, TB, 0, stream>>>(x, src, dst, ew, W0);
    init_kernel<<<elem_blocks, TB, 0, stream>>>(x, W0, cheb, out);

    // k=2: prev1=W0, prev2=x -> W1
    hipMemsetAsync(W1, 0, row_bytes, stream);
    scatter_kernel<<<scatter_blocks, TB, 0, stream>>>(W0, src, dst, ew, W1);
    step_kernel<<<elem_blocks, TB, 0, stream>>>(W1, x, cheb, 2, out);

    // k=3: prev1=W1, prev2=W0 -> W2
    hipMemsetAsync(W2, 0, row_bytes, stream);
    scatter_kernel<<<scatter_blocks, TB, 0, stream>>>(W1, src, dst, ew, W2);
    step_kernel<<<elem_blocks, TB, 0, stream>>>(W2, W0, cheb, 3, out);

    // k=4: prev1=W2, prev2=W1 -> W0
    hipMemsetAsync(W0, 0, row_bytes, stream);
    scatter_kernel<<<scatter_blocks, TB, 0, stream>>>(W2, src, dst, ew, W0);
    step_kernel<<<elem_blocks, TB, 0, stream>>>(W0, W1, cheb, 4, out);

    // k=5: prev1=W0, prev2=W2 -> W1
    hipMemsetAsync(W1, 0, row_bytes, stream);
    scatter_kernel<<<scatter_blocks, TB, 0, stream>>>(W0, src, dst, ew, W1);
    step_kernel<<<elem_blocks, TB, 0, stream>>>(W1, W2, cheb, 5, out);

    // final: scale/bias + RMSNorm + SiLU (in place on out)
    norm_kernel<<<norm_blocks, TB, 0, stream>>>(out, gscale, gbias, rmsw);
}

// Round 2
// 385.144 us; speedup vs baseline: 9.3218x; 9.3218x over previous
//
#include <hip/hip_runtime.h>
#include <math.h>

#define N_NODES 100000
#define N_EDGES 400000
#define HDIM    128
#define GROUPS  4
#define KP1     6      // K+1 coefficients per group
#define RMS_EPS 1.1920929e-07f

#define SCAN_B  256
#define N_SCAN_BLOCKS ((N_NODES + SCAN_B - 1) / SCAN_B)   // 391

// ---------------------------------------------------------------------------
// CSR build step 1: histogram of destination degrees
// ---------------------------------------------------------------------------
__global__ void hist_kernel(const int* __restrict__ dst, int* __restrict__ deg) {
    int e = blockIdx.x * blockDim.x + threadIdx.x;
    if (e >= N_EDGES) return;
    atomicAdd(&deg[dst[e]], 1);
}

// ---------------------------------------------------------------------------
// CSR build step 2a: per-block inclusive scan of deg
// ---------------------------------------------------------------------------
__global__ void scan_local_kernel(const int* __restrict__ deg,
                                  int* __restrict__ inc,
                                  int* __restrict__ blockSums) {
    __shared__ int lds[SCAN_B];
    int i = blockIdx.x * SCAN_B + threadIdx.x;
    int v = (i < N_NODES) ? deg[i] : 0;
    lds[threadIdx.x] = v;
    __syncthreads();
    #pragma unroll
    for (int off = 1; off < SCAN_B; off <<= 1) {
        int t = (threadIdx.x >= off) ? lds[threadIdx.x - off] : 0;
        __syncthreads();
        lds[threadIdx.x] += t;
        __syncthreads();
    }
    if (i < N_NODES) inc[i] = lds[threadIdx.x];
    if (threadIdx.x == SCAN_B - 1) blockSums[blockIdx.x] = lds[SCAN_B - 1];
}

// ---------------------------------------------------------------------------
// CSR build step 2b: exclusive scan of the 391 block sums (single block)
// ---------------------------------------------------------------------------
__global__ void scan_blocks_kernel(int* __restrict__ blockSums) {
    __shared__ int lds[512];
    int v = (threadIdx.x < N_SCAN_BLOCKS) ? blockSums[threadIdx.x] : 0;
    lds[threadIdx.x] = v;
    __syncthreads();
    #pragma unroll
    for (int off = 1; off < 512; off <<= 1) {
        int t = ((int)threadIdx.x >= off) ? lds[threadIdx.x - off] : 0;
        __syncthreads();
        lds[threadIdx.x] += t;
        __syncthreads();
    }
    if (threadIdx.x < N_SCAN_BLOCKS)
        blockSums[threadIdx.x] = (threadIdx.x == 0) ? 0 : lds[threadIdx.x - 1];
}

// ---------------------------------------------------------------------------
// CSR build step 2c: rowptr (exclusive) = inc - deg + blockOffset; cursor copy
// ---------------------------------------------------------------------------
__global__ void finalize_kernel(const int* __restrict__ deg,
                                const int* __restrict__ inc,
                                const int* __restrict__ blockSums,
                                int* __restrict__ rowptr,
                                int* __restrict__ cursor) {
    int i = blockIdx.x * SCAN_B + threadIdx.x;
    if (i >= N_NODES) return;
    int ex = inc[i] - deg[i] + blockSums[i >> 8];
    rowptr[i] = ex;
    cursor[i] = ex;
    if (i == 0) rowptr[N_NODES] = N_EDGES;
}

// ---------------------------------------------------------------------------
// CSR build step 3: fill permuted src / weight arrays
// ---------------------------------------------------------------------------
__global__ void fill_kernel(const int* __restrict__ src,
                            const int* __restrict__ dst,
                            const float* __restrict__ ew,
                            int* __restrict__ cursor,
                            int* __restrict__ esrc,
                            float* __restrict__ ewp) {
    int e = blockIdx.x * blockDim.x + threadIdx.x;
    if (e >= N_EDGES) return;
    int d = dst[e];
    int pos = atomicAdd(&cursor[d], 1);
    esrc[pos] = src[e];
    ewp[pos] = ew[e];
}

// ---------------------------------------------------------------------------
// Fused propagate: one wave (64 lanes) per node, float2 per lane.
//   MODE 0: S = gather(x);   Tc = S;            out  = c0*x + c1*S
//   MODE 1: S = gather(Tp1); Tc = 2S - Tp2;     out += ck*Tc
//   MODE 2: S = gather(Tp1); Tcur = 2S - Tp2;   o = out + ck*Tcur;
//           then group scale/bias -> RMSNorm -> SiLU -> write out (no Tc write)
// ---------------------------------------------------------------------------
template <int MODE>
__global__ void prop_kernel(const float* __restrict__ Tp1,
                            const float* __restrict__ Tp2,
                            const int* __restrict__ rowptr,
                            const int* __restrict__ esrc,
                            const float* __restrict__ ewp,
                            const float* __restrict__ cheb,
                            int k,
                            float* __restrict__ Tc,
                            float* __restrict__ out,
                            const float* __restrict__ gscale,
                            const float* __restrict__ gbias,
                            const float* __restrict__ rmsw) {
    int row  = blockIdx.x * 4 + (threadIdx.x >> 6);   // 4 waves per block
    int lane = threadIdx.x & 63;
    if (row >= N_NODES) return;

    int beg = rowptr[row];
    int end = rowptr[row + 1];

    float2 S = {0.0f, 0.0f};
    for (int j = beg; j < end; ++j) {
        int s   = esrc[j];
        float w = ewp[j];
        float2 v = *reinterpret_cast<const float2*>(Tp1 + (size_t)s * HDIM + lane * 2);
        S.x += w * v.x;
        S.y += w * v.y;
    }

    int g = lane >> 4;                 // group of this float2 (GC = 32)
    size_t off = (size_t)row * HDIM + lane * 2;

    if (MODE == 0) {
        float c0 = cheb[g * KP1 + 0];
        float c1 = cheb[g * KP1 + 1];
        float2 xv = *reinterpret_cast<const float2*>(Tp2 + off);  // Tp2 = x here
        float2 o;
        o.x = c0 * xv.x + c1 * S.x;
        o.y = c0 * xv.y + c1 * S.y;
        *reinterpret_cast<float2*>(Tc + off) = S;
        *reinterpret_cast<float2*>(out + off) = o;
    } else if (MODE == 1) {
        float ck = cheb[g * KP1 + k];
        float2 p = *reinterpret_cast<const float2*>(Tp2 + off);
        float2 t;
        t.x = 2.0f * S.x - p.x;
        t.y = 2.0f * S.y - p.y;
        float2 o = *reinterpret_cast<float2*>(out + off);
        o.x += ck * t.x;
        o.y += ck * t.y;
        *reinterpret_cast<float2*>(Tc + off) = t;
        *reinterpret_cast<float2*>(out + off) = o;
    } else {
        float ck = cheb[g * KP1 + k];
        float2 p = *reinterpret_cast<const float2*>(Tp2 + off);
        float2 t;
        t.x = 2.0f * S.x - p.x;
        t.y = 2.0f * S.y - p.y;
        float2 o = *reinterpret_cast<float2*>(out + off);
        o.x += ck * t.x;
        o.y += ck * t.y;
        // group affine
        float sc = gscale[g];
        float bi = gbias[g];
        o.x = o.x * sc + bi;
        o.y = o.y * sc + bi;
        // RMS over the row (64 lanes x 2)
        float ss = o.x * o.x + o.y * o.y;
        #pragma unroll
        for (int m = 1; m < 64; m <<= 1)
            ss += __shfl_xor(ss, m, 64);
        float r = rsqrtf(ss * (1.0f / HDIM) + RMS_EPS);
        float a = o.x * r * rmsw[lane * 2 + 0];
        float b = o.y * r * rmsw[lane * 2 + 1];
        a = a / (1.0f + expf(-a));
        b = b / (1.0f + expf(-b));
        float2 res = {a, b};
        *reinterpret_cast<float2*>(out + off) = res;
    }
}

// ---------------------------------------------------------------------------
extern "C" void kernel_launch(void* const* d_in, const int* in_sizes, int n_in,
                              void* d_out, int out_size, void* d_ws, size_t ws_size,
                              hipStream_t stream) {
    const float* x      = (const float*)d_in[0];
    const float* ew     = (const float*)d_in[1];
    const float* cheb   = (const float*)d_in[2];
    const float* gscale = (const float*)d_in[3];
    const float* gbias  = (const float*)d_in[4];
    const float* rmsw   = (const float*)d_in[5];
    const int*   eidx   = (const int*)d_in[6];
    const int*   src    = eidx;               // edge_index[0]
    const int*   dst    = eidx + N_EDGES;     // edge_index[1]
    float* out = (float*)d_out;

    // workspace layout
    const size_t NH = (size_t)N_NODES * HDIM;
    float* W0 = (float*)d_ws;
    float* W1 = W0 + NH;
    float* W2 = W1 + NH;
    int*   deg      = (int*)(W2 + NH);
    int*   inc      = deg + N_NODES;
    int*   rowptr   = inc + N_NODES;              // N+1
    int*   cursor   = rowptr + N_NODES + 1;
    int*   blockSums= cursor + N_NODES;           // 512
    int*   esrc     = blockSums + 512;            // E
    float* ewp      = (float*)(esrc + N_EDGES);   // E

    const int TB = 256;
    const int edge_blocks = (N_EDGES + TB - 1) / TB;   // 1563
    const int prop_blocks = (N_NODES + 3) / 4;          // 25000

    // ---- CSR build (by destination) ----
    hipMemsetAsync(deg, 0, N_NODES * sizeof(int), stream);
    hist_kernel<<<edge_blocks, TB, 0, stream>>>(dst, deg);
    scan_local_kernel<<<N_SCAN_BLOCKS, SCAN_B, 0, stream>>>(deg, inc, blockSums);
    scan_blocks_kernel<<<1, 512, 0, stream>>>(blockSums);
    finalize_kernel<<<N_SCAN_BLOCKS, SCAN_B, 0, stream>>>(deg, inc, blockSums, rowptr, cursor);
    fill_kernel<<<edge_blocks, TB, 0, stream>>>(src, dst, ew, cursor, esrc, ewp);

    // ---- fused Chebyshev propagates ----
    // k=1: T1 = prop(x) -> W0 ; out = c0*x + c1*T1
    prop_kernel<0><<<prop_blocks, TB, 0, stream>>>(x, x, rowptr, esrc, ewp, cheb, 1,
                                                   W0, out, gscale, gbias, rmsw);
    // k=2: T2 = 2*prop(W0) - x -> W1 ; out += c2*T2
    prop_kernel<1><<<prop_blocks, TB, 0, stream>>>(W0, x, rowptr, esrc, ewp, cheb, 2,
                                                   W1, out, gscale, gbias, rmsw);
    // k=3: T3 = 2*prop(W1) - W0 -> W2 ; out += c3*T3
    prop_kernel<1><<<prop_blocks, TB, 0, stream>>>(W1, W0, rowptr, esrc, ewp, cheb, 3,
                                                   W2, out, gscale, gbias, rmsw);
    // k=4: T4 = 2*prop(W2) - W1 -> W0 ; out += c4*T4
    prop_kernel<1><<<prop_blocks, TB, 0, stream>>>(W2, W1, rowptr, esrc, ewp, cheb, 4,
                                                   W0, out, gscale, gbias, rmsw);
    // k=5: T5 = 2*prop(W0) - W2 ; out = silu(rmsnorm(gaffine(out + c5*T5)))
    prop_kernel<2><<<prop_blocks, TB, 0, stream>>>(W0, W2, rowptr, esrc, ewp, cheb, 5,
                                                   nullptr, out, gscale, gbias, rmsw);
}

// Round 3
// 274.873 us; speedup vs baseline: 13.0613x; 1.4012x over previous
//
#include <hip/hip_runtime.h>
#include <hip/hip_fp16.h>
#include <math.h>

#define N_NODES 100000
#define N_EDGES 400000
#define HDIM    128
#define KP1     6      // K+1 coefficients per group
#define RMS_EPS 1.1920929e-07f

#define SCAN_B  256
#define N_SCAN_BLOCKS ((N_NODES + SCAN_B - 1) / SCAN_B)   // 391

// ---------------------------------------------------------------------------
// fp16 helpers
// ---------------------------------------------------------------------------
__device__ __forceinline__ float2 h2f(const __half* p) {
    __half2 h = *reinterpret_cast<const __half2*>(p);
    return __half22float2(h);
}
__device__ __forceinline__ void f2h(__half* p, float2 v) {
    *reinterpret_cast<__half2*>(p) = __floats2half2_rn(v.x, v.y);
}

// ---------------------------------------------------------------------------
// CSR build step 1: histogram of destination degrees
// ---------------------------------------------------------------------------
__global__ void hist_kernel(const int* __restrict__ dst, int* __restrict__ deg) {
    int e = blockIdx.x * blockDim.x + threadIdx.x;
    if (e >= N_EDGES) return;
    atomicAdd(&deg[dst[e]], 1);
}

// ---------------------------------------------------------------------------
// CSR build step 2a: per-block inclusive scan of deg
// ---------------------------------------------------------------------------
__global__ void scan_local_kernel(const int* __restrict__ deg,
                                  int* __restrict__ inc,
                                  int* __restrict__ blockSums) {
    __shared__ int lds[SCAN_B];
    int i = blockIdx.x * SCAN_B + threadIdx.x;
    int v = (i < N_NODES) ? deg[i] : 0;
    lds[threadIdx.x] = v;
    __syncthreads();
    #pragma unroll
    for (int off = 1; off < SCAN_B; off <<= 1) {
        int t = (threadIdx.x >= off) ? lds[threadIdx.x - off] : 0;
        __syncthreads();
        lds[threadIdx.x] += t;
        __syncthreads();
    }
    if (i < N_NODES) inc[i] = lds[threadIdx.x];
    if (threadIdx.x == SCAN_B - 1) blockSums[blockIdx.x] = lds[SCAN_B - 1];
}

// ---------------------------------------------------------------------------
// CSR build step 2b: exclusive scan of the 391 block sums (single block)
// ---------------------------------------------------------------------------
__global__ void scan_blocks_kernel(int* __restrict__ blockSums) {
    __shared__ int lds[512];
    int v = (threadIdx.x < N_SCAN_BLOCKS) ? blockSums[threadIdx.x] : 0;
    lds[threadIdx.x] = v;
    __syncthreads();
    #pragma unroll
    for (int off = 1; off < 512; off <<= 1) {
        int t = ((int)threadIdx.x >= off) ? lds[threadIdx.x - off] : 0;
        __syncthreads();
        lds[threadIdx.x] += t;
        __syncthreads();
    }
    if (threadIdx.x < N_SCAN_BLOCKS)
        blockSums[threadIdx.x] = (threadIdx.x == 0) ? 0 : lds[threadIdx.x - 1];
}

// ---------------------------------------------------------------------------
// CSR build step 2c: rowptr (exclusive) = inc - deg + blockOffset; cursor copy
// ---------------------------------------------------------------------------
__global__ void finalize_kernel(const int* __restrict__ deg,
                                const int* __restrict__ inc,
                                const int* __restrict__ blockSums,
                                int* __restrict__ rowptr,
                                int* __restrict__ cursor) {
    int i = blockIdx.x * SCAN_B + threadIdx.x;
    if (i >= N_NODES) return;
    int ex = inc[i] - deg[i] + blockSums[i >> 8];
    rowptr[i] = ex;
    cursor[i] = ex;
    if (i == 0) rowptr[N_NODES] = N_EDGES;
}

// ---------------------------------------------------------------------------
// CSR build step 3: fill packed (src, weight) per slot
// ---------------------------------------------------------------------------
__global__ void fill_kernel(const int* __restrict__ src,
                            const int* __restrict__ dst,
                            const float* __restrict__ ew,
                            int* __restrict__ cursor,
                            int2* __restrict__ epack) {
    int e = blockIdx.x * blockDim.x + threadIdx.x;
    if (e >= N_EDGES) return;
    int d = dst[e];
    int pos = atomicAdd(&cursor[d], 1);
    int2 p;
    p.x = src[e];
    p.y = __float_as_int(ew[e]);
    epack[pos] = p;
}

// ---------------------------------------------------------------------------
// Fused propagate: one wave (64 lanes) per node, 2 dims per lane.
//   MODE 0 (k=1): S = gather_f32(x);   T1 = S;        acc  = c0*x + c1*S
//   MODE 1 (k=2): S = gather_h(Tp1);   T = 2S - x;    acc += ck*T; write T
//   MODE 2 (k=3,4): same but Tp2 is fp16
//   MODE 3 (k=5): T5 in regs; o = acc + c5*T5; group affine -> RMS -> SiLU -> out
// ---------------------------------------------------------------------------
template <int MODE>
__global__ __launch_bounds__(256)
void prop_kernel(const float* __restrict__ xf,
                 const __half* __restrict__ Tp1h,
                 const __half* __restrict__ Tp2h,
                 const int* __restrict__ rowptr,
                 const int2* __restrict__ epack,
                 const float* __restrict__ cheb,
                 int k,
                 __half* __restrict__ Tch,
                 __half* __restrict__ acc,
                 float* __restrict__ out,
                 const float* __restrict__ gscale,
                 const float* __restrict__ gbias,
                 const float* __restrict__ rmsw) {
    int row  = blockIdx.x * 4 + (threadIdx.x >> 6);   // 4 waves per block
    int lane = threadIdx.x & 63;
    if (row >= N_NODES) return;

    int beg = rowptr[row];
    int end = rowptr[row + 1];

    auto gat = [&](int s) -> float2 {
        if (MODE == 0) {
            return *reinterpret_cast<const float2*>(xf + (size_t)s * HDIM + lane * 2);
        } else {
            return h2f(Tp1h + (size_t)s * HDIM + lane * 2);
        }
    };

    float2 S = {0.0f, 0.0f};
    int j = beg;
    // 4-wide unroll for memory-level parallelism
    for (; j + 3 < end; j += 4) {
        int2 e0 = epack[j], e1 = epack[j + 1], e2 = epack[j + 2], e3 = epack[j + 3];
        float2 v0 = gat(e0.x), v1 = gat(e1.x), v2 = gat(e2.x), v3 = gat(e3.x);
        float w0 = __int_as_float(e0.y), w1 = __int_as_float(e1.y);
        float w2 = __int_as_float(e2.y), w3 = __int_as_float(e3.y);
        S.x += w0 * v0.x + w1 * v1.x + w2 * v2.x + w3 * v3.x;
        S.y += w0 * v0.y + w1 * v1.y + w2 * v2.y + w3 * v3.y;
    }
    for (; j < end; ++j) {
        int2 e0 = epack[j];
        float2 v0 = gat(e0.x);
        float w = __int_as_float(e0.y);
        S.x += w * v0.x;
        S.y += w * v0.y;
    }

    int g = lane >> 4;                 // group of this 2-dim chunk (GC = 32)
    size_t off = (size_t)row * HDIM + lane * 2;

    if (MODE == 0) {
        float c0 = cheb[g * KP1 + 0];
        float c1 = cheb[g * KP1 + 1];
        float2 xv = *reinterpret_cast<const float2*>(xf + off);
        f2h(Tch + off, S);
        float2 a = {c0 * xv.x + c1 * S.x, c0 * xv.y + c1 * S.y};
        f2h(acc + off, a);
    } else if (MODE == 1 || MODE == 2) {
        float ck = cheb[g * KP1 + k];
        float2 p;
        if (MODE == 1) p = *reinterpret_cast<const float2*>(xf + off);
        else           p = h2f(Tp2h + off);
        float2 t = {2.0f * S.x - p.x, 2.0f * S.y - p.y};
        f2h(Tch + off, t);
        float2 a = h2f(acc + off);
        a.x += ck * t.x;
        a.y += ck * t.y;
        f2h(acc + off, a);
    } else {
        float ck = cheb[g * KP1 + k];
        float2 p = h2f(Tp2h + off);
        float2 t = {2.0f * S.x - p.x, 2.0f * S.y - p.y};
        float2 o = h2f(acc + off);
        o.x += ck * t.x;
        o.y += ck * t.y;
        // group affine
        float sc = gscale[g];
        float bi = gbias[g];
        o.x = o.x * sc + bi;
        o.y = o.y * sc + bi;
        // RMS over the row (64 lanes x 2)
        float ss = o.x * o.x + o.y * o.y;
        #pragma unroll
        for (int m = 1; m < 64; m <<= 1)
            ss += __shfl_xor(ss, m, 64);
        float r = rsqrtf(ss * (1.0f / HDIM) + RMS_EPS);
        float a = o.x * r * rmsw[lane * 2 + 0];
        float b = o.y * r * rmsw[lane * 2 + 1];
        a = a / (1.0f + expf(-a));
        b = b / (1.0f + expf(-b));
        float2 res = {a, b};
        *reinterpret_cast<float2*>(out + off) = res;
    }
}

// ---------------------------------------------------------------------------
extern "C" void kernel_launch(void* const* d_in, const int* in_sizes, int n_in,
                              void* d_out, int out_size, void* d_ws, size_t ws_size,
                              hipStream_t stream) {
    const float* x      = (const float*)d_in[0];
    const float* ew     = (const float*)d_in[1];
    const float* cheb   = (const float*)d_in[2];
    const float* gscale = (const float*)d_in[3];
    const float* gbias  = (const float*)d_in[4];
    const float* rmsw   = (const float*)d_in[5];
    const int*   eidx   = (const int*)d_in[6];
    const int*   src    = eidx;               // edge_index[0]
    const int*   dst    = eidx + N_EDGES;     // edge_index[1]
    float* out = (float*)d_out;

    // workspace layout
    const size_t NH = (size_t)N_NODES * HDIM;
    __half* T1  = (__half*)d_ws;
    __half* T2  = T1 + NH;
    __half* T3  = T2 + NH;
    __half* T4  = T3 + NH;
    __half* acc = T4 + NH;
    int2*  epack    = (int2*)(acc + NH);          // E entries (8B-aligned: 5*NH*2 = 128e6)
    int*   deg      = (int*)(epack + N_EDGES);
    int*   inc      = deg + N_NODES;
    int*   rowptr   = inc + N_NODES;              // N+1
    int*   cursor   = rowptr + N_NODES + 1;
    int*   blockSums= cursor + N_NODES;           // 512

    const int TB = 256;
    const int edge_blocks = (N_EDGES + TB - 1) / TB;    // 1563
    const int prop_blocks = (N_NODES + 3) / 4;          // 25000

    // ---- CSR build (by destination) ----
    hipMemsetAsync(deg, 0, N_NODES * sizeof(int), stream);
    hist_kernel<<<edge_blocks, TB, 0, stream>>>(dst, deg);
    scan_local_kernel<<<N_SCAN_BLOCKS, SCAN_B, 0, stream>>>(deg, inc, blockSums);
    scan_blocks_kernel<<<1, 512, 0, stream>>>(blockSums);
    finalize_kernel<<<N_SCAN_BLOCKS, SCAN_B, 0, stream>>>(deg, inc, blockSums, rowptr, cursor);
    fill_kernel<<<edge_blocks, TB, 0, stream>>>(src, dst, ew, cursor, epack);

    // ---- fused Chebyshev propagates (fp16 intermediates) ----
    // k=1: T1 = prop(x); acc = c0*x + c1*T1
    prop_kernel<0><<<prop_blocks, TB, 0, stream>>>(x, nullptr, nullptr, rowptr, epack,
                                                   cheb, 1, T1, acc, out, gscale, gbias, rmsw);
    // k=2: T2 = 2*prop(T1) - x; acc += c2*T2
    prop_kernel<1><<<prop_blocks, TB, 0, stream>>>(x, T1, nullptr, rowptr, epack,
                                                   cheb, 2, T2, acc, out, gscale, gbias, rmsw);
    // k=3: T3 = 2*prop(T2) - T1; acc += c3*T3
    prop_kernel<2><<<prop_blocks, TB, 0, stream>>>(x, T2, T1, rowptr, epack,
                                                   cheb, 3, T3, acc, out, gscale, gbias, rmsw);
    // k=4: T4 = 2*prop(T3) - T2; acc += c4*T4
    prop_kernel<2><<<prop_blocks, TB, 0, stream>>>(x, T3, T2, rowptr, epack,
                                                   cheb, 4, T4, acc, out, gscale, gbias, rmsw);
    // k=5: T5 = 2*prop(T4) - T3 (regs); out = silu(rms(gaffine(acc + c5*T5)))
    prop_kernel<3><<<prop_blocks, TB, 0, stream>>>(x, T4, T3, rowptr, epack,
                                                   cheb, 5, nullptr, acc, out, gscale, gbias, rmsw);
}

// Round 4
// 207.802 us; speedup vs baseline: 17.2771x; 1.3228x over previous
//
#include <hip/hip_runtime.h>
#include <hip/hip_fp16.h>
#include <math.h>

#define N_NODES 100000
#define N_EDGES 400000
#define HDIM    128
#define KP1     6      // K+1 coefficients per group
#define RMS_EPS 1.1920929e-07f

#define SCAN_B  256
#define N_SCAN_BLOCKS ((N_NODES + SCAN_B - 1) / SCAN_B)   // 391

// ---------------------------------------------------------------------------
// CSR build step 1: histogram of destination degrees
// ---------------------------------------------------------------------------
__global__ void hist_kernel(const int* __restrict__ dst, int* __restrict__ deg) {
    int e = blockIdx.x * blockDim.x + threadIdx.x;
    if (e >= N_EDGES) return;
    atomicAdd(&deg[dst[e]], 1);
}

// ---------------------------------------------------------------------------
// CSR build step 2a: per-block inclusive scan of deg
// ---------------------------------------------------------------------------
__global__ void scan_local_kernel(const int* __restrict__ deg,
                                  int* __restrict__ inc,
                                  int* __restrict__ blockSums) {
    __shared__ int lds[SCAN_B];
    int i = blockIdx.x * SCAN_B + threadIdx.x;
    int v = (i < N_NODES) ? deg[i] : 0;
    lds[threadIdx.x] = v;
    __syncthreads();
    #pragma unroll
    for (int off = 1; off < SCAN_B; off <<= 1) {
        int t = (threadIdx.x >= off) ? lds[threadIdx.x - off] : 0;
        __syncthreads();
        lds[threadIdx.x] += t;
        __syncthreads();
    }
    if (i < N_NODES) inc[i] = lds[threadIdx.x];
    if (threadIdx.x == SCAN_B - 1) blockSums[blockIdx.x] = lds[SCAN_B - 1];
}

// ---------------------------------------------------------------------------
// CSR build step 2b: exclusive scan of the 391 block sums (single block)
// ---------------------------------------------------------------------------
__global__ void scan_blocks_kernel(int* __restrict__ blockSums) {
    __shared__ int lds[512];
    int v = (threadIdx.x < N_SCAN_BLOCKS) ? blockSums[threadIdx.x] : 0;
    lds[threadIdx.x] = v;
    __syncthreads();
    #pragma unroll
    for (int off = 1; off < 512; off <<= 1) {
        int t = ((int)threadIdx.x >= off) ? lds[threadIdx.x - off] : 0;
        __syncthreads();
        lds[threadIdx.x] += t;
        __syncthreads();
    }
    if (threadIdx.x < N_SCAN_BLOCKS)
        blockSums[threadIdx.x] = (threadIdx.x == 0) ? 0 : lds[threadIdx.x - 1];
}

// ---------------------------------------------------------------------------
// CSR build step 2c: rowptr (exclusive) = inc - deg + blockOffset; cursor copy
// ---------------------------------------------------------------------------
__global__ void finalize_kernel(const int* __restrict__ deg,
                                const int* __restrict__ inc,
                                const int* __restrict__ blockSums,
                                int* __restrict__ rowptr,
                                int* __restrict__ cursor) {
    int i = blockIdx.x * SCAN_B + threadIdx.x;
    if (i >= N_NODES) return;
    int ex = inc[i] - deg[i] + blockSums[i >> 8];
    rowptr[i] = ex;
    cursor[i] = ex;
    if (i == 0) rowptr[N_NODES] = N_EDGES;
}

// ---------------------------------------------------------------------------
// CSR build step 3: fill packed (src_row_offset, weight) per slot
// ---------------------------------------------------------------------------
__global__ void fill_kernel(const int* __restrict__ src,
                            const int* __restrict__ dst,
                            const float* __restrict__ ew,
                            int* __restrict__ cursor,
                            int2* __restrict__ epack) {
    int e = blockIdx.x * blockDim.x + threadIdx.x;
    if (e >= N_EDGES) return;
    int d = dst[e];
    int pos = atomicAdd(&cursor[d], 1);
    int2 p;
    p.x = src[e] * HDIM;                 // element offset of source row
    p.y = __float_as_int(ew[e]);
    epack[pos] = p;
}

// ---------------------------------------------------------------------------
// helpers: 8-dim fragments per lane
// ---------------------------------------------------------------------------
__device__ __forceinline__ void fma8_h(const __half* __restrict__ p, float w, float* S) {
    int4 r = *reinterpret_cast<const int4*>(p);       // 8 halves
    const __half2* h = reinterpret_cast<const __half2*>(&r);
    #pragma unroll
    for (int q = 0; q < 4; ++q) {
        float2 f = __half22float2(h[q]);
        S[2 * q + 0] += w * f.x;
        S[2 * q + 1] += w * f.y;
    }
}
__device__ __forceinline__ void fma8_f(const float* __restrict__ p, float w, float* S) {
    float4 a = *reinterpret_cast<const float4*>(p);
    float4 b = *reinterpret_cast<const float4*>(p + 4);
    S[0] += w * a.x; S[1] += w * a.y; S[2] += w * a.z; S[3] += w * a.w;
    S[4] += w * b.x; S[5] += w * b.y; S[6] += w * b.z; S[7] += w * b.w;
}
__device__ __forceinline__ void load8_h(const __half* __restrict__ p, float* o) {
    int4 r = *reinterpret_cast<const int4*>(p);
    const __half2* h = reinterpret_cast<const __half2*>(&r);
    #pragma unroll
    for (int q = 0; q < 4; ++q) {
        float2 f = __half22float2(h[q]);
        o[2 * q + 0] = f.x;
        o[2 * q + 1] = f.y;
    }
}
__device__ __forceinline__ void store8_h(__half* __restrict__ p, const float* v) {
    int4 r;
    __half2* h = reinterpret_cast<__half2*>(&r);
    #pragma unroll
    for (int q = 0; q < 4; ++q)
        h[q] = __floats2half2_rn(v[2 * q + 0], v[2 * q + 1]);
    *reinterpret_cast<int4*>(p) = r;
}

// ---------------------------------------------------------------------------
// Fused propagate: 16 lanes per node (8 dims/lane), 4 nodes per wave,
// 16 nodes per 256-thread block. 4x unrolled gather loop -> 16B/lane loads.
//   MODE 0 (k=1): S = gather_f32(x);  write T1 = S
//   MODE 1 (k=2): S = gather_h(T1);   write T2 = 2S - x (x is f32)
//   MODE 2 (k=3,4): S = gather_h(Tp1); write Tc = 2S - Tp2 (fp16)
//   MODE 3 (k=5): S = gather_h(T4); T5 = 2S - T3;
//                 o = c0*x + c1*T1 + c2*T2 + c3*T3 + c4*T4 + c5*T5;
//                 group affine -> RMSNorm -> SiLU -> out (f32)
// ---------------------------------------------------------------------------
template <int MODE>
__global__ __launch_bounds__(256)
void prop_kernel(const float* __restrict__ xf,
                 const __half* __restrict__ Tp1h,   // gather source (fp16 modes)
                 const __half* __restrict__ Tp2h,
                 const int* __restrict__ rowptr,
                 const int2* __restrict__ epack,
                 const float* __restrict__ cheb,
                 int k,
                 __half* __restrict__ Tch,
                 const __half* __restrict__ T1h,    // MODE 3 only
                 const __half* __restrict__ T2h,    // MODE 3 only
                 float* __restrict__ out,
                 const float* __restrict__ gscale,
                 const float* __restrict__ gbias,
                 const float* __restrict__ rmsw) {
    int grp = threadIdx.x >> 4;                  // 16-lane group id within block
    int sub = threadIdx.x & 15;                  // lane within group
    int row = blockIdx.x * 16 + grp;
    if (row >= N_NODES) return;

    int beg = rowptr[row];
    int end = rowptr[row + 1];
    int d8 = sub * 8;                            // dim offset of this lane

    float S[8] = {0, 0, 0, 0, 0, 0, 0, 0};
    int j = beg;
    for (; j + 3 < end; j += 4) {
        int2 e0 = epack[j], e1 = epack[j + 1], e2 = epack[j + 2], e3 = epack[j + 3];
        float w0 = __int_as_float(e0.y), w1 = __int_as_float(e1.y);
        float w2 = __int_as_float(e2.y), w3 = __int_as_float(e3.y);
        if (MODE == 0) {
            fma8_f(xf + e0.x + d8, w0, S);
            fma8_f(xf + e1.x + d8, w1, S);
            fma8_f(xf + e2.x + d8, w2, S);
            fma8_f(xf + e3.x + d8, w3, S);
        } else {
            fma8_h(Tp1h + e0.x + d8, w0, S);
            fma8_h(Tp1h + e1.x + d8, w1, S);
            fma8_h(Tp1h + e2.x + d8, w2, S);
            fma8_h(Tp1h + e3.x + d8, w3, S);
        }
    }
    for (; j < end; ++j) {
        int2 e0 = epack[j];
        float w = __int_as_float(e0.y);
        if (MODE == 0) fma8_f(xf + e0.x + d8, w, S);
        else           fma8_h(Tp1h + e0.x + d8, w, S);
    }

    size_t off = (size_t)row * HDIM + d8;
    int g = sub >> 2;                            // group index (32 dims per group)

    if (MODE == 0) {
        store8_h(Tch + off, S);
    } else if (MODE == 1) {
        float4 pa = *reinterpret_cast<const float4*>(xf + off);
        float4 pb = *reinterpret_cast<const float4*>(xf + off + 4);
        float t[8];
        t[0] = 2.0f * S[0] - pa.x; t[1] = 2.0f * S[1] - pa.y;
        t[2] = 2.0f * S[2] - pa.z; t[3] = 2.0f * S[3] - pa.w;
        t[4] = 2.0f * S[4] - pb.x; t[5] = 2.0f * S[5] - pb.y;
        t[6] = 2.0f * S[6] - pb.z; t[7] = 2.0f * S[7] - pb.w;
        store8_h(Tch + off, t);
    } else if (MODE == 2) {
        float p[8];
        load8_h(Tp2h + off, p);
        float t[8];
        #pragma unroll
        for (int q = 0; q < 8; ++q) t[q] = 2.0f * S[q] - p[q];
        store8_h(Tch + off, t);
    } else {
        // final: full polynomial sum + epilogue
        float t3[8], t1[8], t2[8], t4[8];
        load8_h(Tp2h + off, t3);       // T3 row
        load8_h(T1h + off, t1);
        load8_h(T2h + off, t2);
        load8_h(Tp1h + off, t4);       // T4 row (same buffer we gathered from)
        float4 xa = *reinterpret_cast<const float4*>(xf + off);
        float4 xb = *reinterpret_cast<const float4*>(xf + off + 4);
        float xr[8] = {xa.x, xa.y, xa.z, xa.w, xb.x, xb.y, xb.z, xb.w};

        float c0 = cheb[g * KP1 + 0], c1 = cheb[g * KP1 + 1], c2 = cheb[g * KP1 + 2];
        float c3 = cheb[g * KP1 + 3], c4 = cheb[g * KP1 + 4], c5 = cheb[g * KP1 + 5];
        float sc = gscale[g];
        float bi = gbias[g];

        float o[8];
        float ss = 0.0f;
        #pragma unroll
        for (int q = 0; q < 8; ++q) {
            float t5 = 2.0f * S[q] - t3[q];
            float v = c0 * xr[q] + c1 * t1[q] + c2 * t2[q] + c3 * t3[q]
                    + c4 * t4[q] + c5 * t5;
            v = v * sc + bi;
            o[q] = v;
            ss += v * v;
        }
        // reduce over the 16 lanes of this group (masks 1,2,4,8 stay in-group)
        #pragma unroll
        for (int m = 1; m < 16; m <<= 1)
            ss += __shfl_xor(ss, m, 64);
        float r = rsqrtf(ss * (1.0f / HDIM) + RMS_EPS);

        float4 wa = *reinterpret_cast<const float4*>(rmsw + d8);
        float4 wb = *reinterpret_cast<const float4*>(rmsw + d8 + 4);
        float wv[8] = {wa.x, wa.y, wa.z, wa.w, wb.x, wb.y, wb.z, wb.w};
        float res[8];
        #pragma unroll
        for (int q = 0; q < 8; ++q) {
            float a = o[q] * r * wv[q];
            res[q] = a / (1.0f + expf(-a));
        }
        float4 ra = {res[0], res[1], res[2], res[3]};
        float4 rb = {res[4], res[5], res[6], res[7]};
        *reinterpret_cast<float4*>(out + off) = ra;
        *reinterpret_cast<float4*>(out + off + 4) = rb;
    }
}

// ---------------------------------------------------------------------------
extern "C" void kernel_launch(void* const* d_in, const int* in_sizes, int n_in,
                              void* d_out, int out_size, void* d_ws, size_t ws_size,
                              hipStream_t stream) {
    const float* x      = (const float*)d_in[0];
    const float* ew     = (const float*)d_in[1];
    const float* cheb   = (const float*)d_in[2];
    const float* gscale = (const float*)d_in[3];
    const float* gbias  = (const float*)d_in[4];
    const float* rmsw   = (const float*)d_in[5];
    const int*   eidx   = (const int*)d_in[6];
    const int*   src    = eidx;               // edge_index[0]
    const int*   dst    = eidx + N_EDGES;     // edge_index[1]
    float* out = (float*)d_out;

    // workspace layout
    const size_t NH = (size_t)N_NODES * HDIM;
    __half* T1  = (__half*)d_ws;
    __half* T2  = T1 + NH;
    __half* T3  = T2 + NH;
    __half* T4  = T3 + NH;
    int2*  epack    = (int2*)(T4 + NH);           // E entries
    int*   deg      = (int*)(epack + N_EDGES);
    int*   inc      = deg + N_NODES;
    int*   rowptr   = inc + N_NODES;              // N+1
    int*   cursor   = rowptr + N_NODES + 1;
    int*   blockSums= cursor + N_NODES;           // 512

    const int TB = 256;
    const int edge_blocks = (N_EDGES + TB - 1) / TB;    // 1563
    const int prop_blocks = (N_NODES + 15) / 16;        // 6250

    // ---- CSR build (by destination) ----
    hipMemsetAsync(deg, 0, N_NODES * sizeof(int), stream);
    hist_kernel<<<edge_blocks, TB, 0, stream>>>(dst, deg);
    scan_local_kernel<<<N_SCAN_BLOCKS, SCAN_B, 0, stream>>>(deg, inc, blockSums);
    scan_blocks_kernel<<<1, 512, 0, stream>>>(blockSums);
    finalize_kernel<<<N_SCAN_BLOCKS, SCAN_B, 0, stream>>>(deg, inc, blockSums, rowptr, cursor);
    fill_kernel<<<edge_blocks, TB, 0, stream>>>(src, dst, ew, cursor, epack);

    // ---- fused Chebyshev propagates (fp16 intermediates, no acc buffer) ----
    // k=1: T1 = prop(x)
    prop_kernel<0><<<prop_blocks, TB, 0, stream>>>(x, nullptr, nullptr, rowptr, epack,
                                                   cheb, 1, T1, nullptr, nullptr,
                                                   out, gscale, gbias, rmsw);
    // k=2: T2 = 2*prop(T1) - x
    prop_kernel<1><<<prop_blocks, TB, 0, stream>>>(x, T1, nullptr, rowptr, epack,
                                                   cheb, 2, T2, nullptr, nullptr,
                                                   out, gscale, gbias, rmsw);
    // k=3: T3 = 2*prop(T2) - T1
    prop_kernel<2><<<prop_blocks, TB, 0, stream>>>(nullptr, T2, T1, rowptr, epack,
                                                   cheb, 3, T3, nullptr, nullptr,
                                                   out, gscale, gbias, rmsw);
    // k=4: T4 = 2*prop(T3) - T2
    prop_kernel<2><<<prop_blocks, TB, 0, stream>>>(nullptr, T3, T2, rowptr, epack,
                                                   cheb, 4, T4, nullptr, nullptr,
                                                   out, gscale, gbias, rmsw);
    // k=5: T5 = 2*prop(T4) - T3; out = silu(rms(gaffine(sum c_k T_k)))
    prop_kernel<3><<<prop_blocks, TB, 0, stream>>>(x, T4, T3, rowptr, epack,
                                                   cheb, 5, nullptr, T1, T2,
                                                   out, gscale, gbias, rmsw);
}